// Round 12
// baseline (313.433 us; speedup 1.0000x reference)
//
#include <hip/hip_runtime.h>
#include <math.h>

#define NTHREADS 512
#define TOUT 252
#define NDIF 264
#define NUU 266

// element strides (u16)
#define X1S 40              // x1: cols 0..19 data, 20..31 zero (q=3 frag reads), 32..39 unused
#define X2S 40              // x2 / x4 share bufB
#define T3AS 34             // t3 phase A (ch 0..31):  34 u16 = 17 banks, odd -> conflict-free
#define T3BS 50             // t3 phase B (ch 32..79): 50 u16 = 25 banks, odd -> conflict-free
#define X5S 26              // odd bank stride for conv6

// smem regions (bytes, 16B aligned)
#define SUU_OFF  0          // float[266]  = 1064
#define SDIF_OFF 1072       // float[264]  = 1056
#define RA_OFF   2144       // region A: x1(20800) -> t3A(17408) -> t3B(25600) -> x5(13312) = 25600
#define RB_OFF   27744      // x2/x4: 258x40x2 = 20640 ; beta float[256] overlays
#define SMEM_SIZE 48384     // -> 3 blocks/CU

// weight-fragment table in d_ws: 42 frags x 64 lanes x 8 bf16 (16 B)
#define F2_BASE 0           // conv2: 15 frags (mt 0..2, s 0..4)
#define F3_BASE 15          // conv3: 10 frags (mt 0..4, s 0..1)
#define F4_BASE 25          // conv4: 9  frags (mt 0..2, s 0..2)
#define F5_BASE 34          // conv5: 8  frags (mt 0..1, s 0..3)
#define NFRAGS 42

typedef unsigned short u16;
typedef unsigned int u32;
typedef __attribute__((ext_vector_type(8))) short bf16x8;
typedef __attribute__((ext_vector_type(4))) float f32x4;

__device__ __forceinline__ float elu_f(float x) {
    return x > 0.0f ? x : (__expf(x) - 1.0f);
}
__device__ __forceinline__ float sq_f(float x) { return x * x; }
__device__ __forceinline__ u16 f2bf(float f) {              // RNE (setup kernel only)
    union { float f; u32 u; } v; v.f = f;
    u32 r = v.u + 0x7FFFu + ((v.u >> 16) & 1u);
    return (u16)(r >> 16);
}
__device__ __forceinline__ float bf_lo(u32 u) {
    union { u32 u; float f; } v; v.u = u << 16; return v.f;
}
__device__ __forceinline__ float bf_hi(u32 u) {
    union { u32 u; float f; } v; v.u = u & 0xFFFF0000u; return v.f;
}
__device__ __forceinline__ u32 pack_trunc(float a, float b) {
    union { float f; u32 u; } va, vb; va.f = a; vb.f = b;
#if __has_builtin(__builtin_amdgcn_perm)
    return __builtin_amdgcn_perm(vb.u, va.u, 0x07060302u);
#else
    return (vb.u & 0xFFFF0000u) | (va.u >> 16);
#endif
}

// ---- setup kernel: build all MFMA A-operand weight frags once per launch ----
__global__ __launch_bounds__(64) void build_frags_kernel(
    const float* __restrict__ w2, const float* __restrict__ w3,
    const float* __restrict__ w4, const float* __restrict__ w5,
    u16* __restrict__ ws)
{
    const int f = blockIdx.x;      // 0..41
    const int lane = threadIdx.x;  // 0..63
    const int m = lane & 15;
    const int q = lane >> 4;
    float wvv[8];
    #pragma unroll
    for (int j = 0; j < 8; ++j) wvv[j] = 0.0f;

    if (f < F3_BASE) {                       // conv2: 20->40 k=5, K = dk*32+ic
        int mt = (f - F2_BASE) / 5, s = (f - F2_BASE) % 5;
        int oc = mt * 16 + m;
        #pragma unroll
        for (int j = 0; j < 8; ++j) {
            int ic = q * 8 + j;
            if (oc < 40 && ic < 20) wvv[j] = w2[oc * 100 + ic * 5 + s];
        }
    } else if (f < F4_BASE) {                // conv3: 40->80 k=1, K=40 pad 64
        int mt = (f - F3_BASE) / 2, s = (f - F3_BASE) % 2;
        int oc = mt * 16 + m;
        #pragma unroll
        for (int j = 0; j < 8; ++j) {
            int k = s * 32 + q * 8 + j;
            if (k < 40) wvv[j] = w3[oc * 40 + k];
        }
    } else if (f < F5_BASE) {                // conv4: 80->40 k=1, K=80 pad 96
        int mt = (f - F4_BASE) / 3, s = (f - F4_BASE) % 3;
        int oc = mt * 16 + m;
        #pragma unroll
        for (int j = 0; j < 8; ++j) {
            int k = s * 32 + q * 8 + j;
            if (oc < 40 && k < 80) wvv[j] = w4[oc * 80 + k];
        }
    } else {                                 // conv5: 40->20 k=3, K=120: k=dk*40+ic
        int mt = (f - F5_BASE) / 4, s = (f - F5_BASE) % 4;
        int oc = mt * 16 + m;
        int k0 = s * 32 + q * 8;
        int dk = k0 / 40, ic0 = k0 - dk * 40;
        #pragma unroll
        for (int j = 0; j < 8; ++j) {
            if (oc < 20 && k0 < 120) wvv[j] = w5[oc * 120 + (ic0 + j) * 3 + dk];
        }
    }
    u32 pk[4];
    #pragma unroll
    for (int p = 0; p < 4; ++p)
        pk[p] = (u32)f2bf(wvv[2 * p]) | ((u32)f2bf(wvv[2 * p + 1]) << 16);
    u32* wp = (u32*)&ws[(f * 64 + lane) * 8];
    wp[0] = pk[0]; wp[1] = pk[1]; wp[2] = pk[2]; wp[3] = pk[3];
}

__device__ __forceinline__ bf16x8 ld_frag(const u16* ws, int f, int lane) {
    return *(const bf16x8*)&ws[(f * 64 + lane) * 8];
}

// plain (512): LDS (48.4KB -> 3 blocks/CU) caps occupancy; min-waves bounds
// previously forced spills (R5: 500MB, R10: 25MB).
__global__ __launch_bounds__(NTHREADS) void weno_nn_kernel(
    const float* __restrict__ uu, const float* __restrict__ e_ptr,
    const float* __restrict__ w1, const float* __restrict__ b1,
    const float* __restrict__ b2, const float* __restrict__ b3,
    const float* __restrict__ b4, const float* __restrict__ b5,
    const float* __restrict__ w6, const float* __restrict__ b6,
    const u16* __restrict__ wfr,
    float* __restrict__ out, int n_out, int N)
{
    __shared__ __align__(16) unsigned char smem[SMEM_SIZE];
    float* s_uu  = (float*)(smem + SUU_OFF);
    float* s_dif = (float*)(smem + SDIF_OFF);
    u16*   x1    = (u16*)(smem + RA_OFF);
    u16*   t3a   = (u16*)(smem + RA_OFF);    // overlays x1 (dead after conv2)
    u16*   t3b   = (u16*)(smem + RA_OFF);    // overlays t3a (dead after conv4 s0)
    u16*   x5    = (u16*)(smem + RA_OFF);    // overlays t3b (dead after conv4 fin)
    u16*   xB    = (u16*)(smem + RB_OFF);    // x2 -> x4 (own-row overwrite)
    float* beta  = (float*)(smem + RB_OFF);  // overlays x4 (dead after conv5)

    const int tid  = threadIdx.x;
    const int lane = tid & 63;
    const int wv   = __builtin_amdgcn_readfirstlane(tid >> 6);   // 0..7
    const int m    = lane & 15;
    const int q    = lane >> 4;
    const int J0   = blockIdx.x * TOUT;
    const int P0   = J0 + 2;
    const int U0   = J0 - 4;

    // ---------- stage 0: uu tile ----------
    for (int i = tid; i < NUU; i += NTHREADS) {
        int g = U0 + i;
        s_uu[i] = (g >= 0 && g < N) ? uu[g] : 0.0f;
    }
    __syncthreads();

    // ---------- avg-diff ----------
    for (int d = tid; d < NDIF; d += NTHREADS) {
        int g = P0 - 5 + d;
        float v = 0.0f;
        if (g >= 0 && g < N) {
            int j1 = g < N - 2 ? g : N - 2;
            int j0 = g - 1 > 0 ? g - 1 : 0;
            float dl = s_uu[j1 + 1 - U0] - s_uu[j1 - U0];
            float dr = s_uu[j0 + 1 - U0] - s_uu[j0 - U0];
            v = 0.5f * (dl + dr);
        }
        s_dif[d] = v;
    }
    __syncthreads();

    // ---------- conv1 (VALU): 1->20, k=5, elu -> x1[row][ic] ----------
    if (tid < 40) ((u32*)&xB[256 * X2S])[tid] = 0;   // zero x4 rows 256,257 (conv5 edge)
    for (int s = tid; s < 260; s += NTHREADS) {
        int g = P0 - 3 + s;
        bool valid = (g >= 0 && g < N);
        float dv[5];
        #pragma unroll
        for (int k = 0; k < 5; ++k) dv[k] = s_dif[s + k];
        float v[20];
        #pragma unroll
        for (int oc = 0; oc < 20; ++oc) {
            float a = b1[oc];
            #pragma unroll
            for (int k = 0; k < 5; ++k) a += w1[oc * 5 + k] * dv[k];
            v[oc] = valid ? elu_f(a) : 0.0f;
        }
        u32* rp = (u32*)&x1[s * X1S];
        #pragma unroll
        for (int p = 0; p < 10; ++p)
            rp[p] = pack_trunc(v[2 * p], v[2 * p + 1]);
        #pragma unroll
        for (int p = 10; p < 16; ++p) rp[p] = 0;     // zero-pad ic 20..31
    }
    __syncthreads();

    // ---------- conv2: 20->40, k=5 (im2col K=160) -> xB(x2) ----------
    {
        bf16x8 a2[3][5];
        #pragma unroll
        for (int mt = 0; mt < 3; ++mt)
            #pragma unroll
            for (int s = 0; s < 5; ++s)
                a2[mt][s] = ld_frag(wfr, F2_BASE + mt * 5 + s, lane);
        f32x4 bias2[3];
        #pragma unroll
        for (int mt = 0; mt < 3; ++mt) {
            #pragma unroll
            for (int r = 0; r < 4; ++r) {
                int oc = mt * 16 + 4 * q + r;
                bias2[mt][r] = (oc < 40) ? b2[oc] : 0.0f;
            }
        }
        for (int t = 0; t < 2; ++t) {
            const int N0 = (wv * 2 + t) * 16;
            f32x4 acc[3];
            #pragma unroll
            for (int mt = 0; mt < 3; ++mt) acc[mt] = bias2[mt];
            #pragma unroll
            for (int s = 0; s < 5; ++s) {
                bf16x8 bfrag = *(const bf16x8*)&x1[(N0 + m + s) * X1S + q * 8];
                #pragma unroll
                for (int mt = 0; mt < 3; ++mt)
                    acc[mt] = __builtin_amdgcn_mfma_f32_16x16x32_bf16(a2[mt][s], bfrag, acc[mt], 0, 0, 0);
            }
            #pragma unroll
            for (int mt = 0; mt < 3; ++mt) {
                int oc0 = mt * 16 + 4 * q;
                if (oc0 < 40) {
                    u32* wp = (u32*)&xB[(N0 + m) * X2S + oc0];
                    wp[0] = pack_trunc(elu_f(acc[mt][0]), elu_f(acc[mt][1]));
                    wp[1] = pack_trunc(elu_f(acc[mt][2]), elu_f(acc[mt][3]));
                }
            }
        }
    }
    __syncthreads();

    // ---------- conv3/conv4 split-K: A = ch 0..31, B = ch 32..79 ----------
    bf16x8 Bx2[2][2];                 // x2 B-frags, reused in both conv3 phases
    f32x4  acc4[2][3];                // conv4 accumulators persist across phases
    #pragma unroll
    for (int t = 0; t < 2; ++t) {
        #pragma unroll
        for (int mt = 0; mt < 3; ++mt) {
            #pragma unroll
            for (int r = 0; r < 4; ++r) {
                int oc = mt * 16 + 4 * q + r;
                acc4[t][mt][r] = (oc < 40) ? b4[oc] : 0.0f;
            }
        }
    }

    // conv3 phase A: oc 0..31 -> t3a
    for (int t = 0; t < 2; ++t) {
        const int rowi = (wv * 2 + t) * 16 + m;
        Bx2[t][0] = *(const bf16x8*)&xB[rowi * X2S + q * 8];
        Bx2[t][1] = *(const bf16x8*)&xB[rowi * X2S + ((q == 0) ? 32 : 0)];
        #pragma unroll
        for (int mt = 0; mt < 2; ++mt) {
            f32x4 a3;
            #pragma unroll
            for (int r = 0; r < 4; ++r) a3[r] = b3[mt * 16 + 4 * q + r];
            a3 = __builtin_amdgcn_mfma_f32_16x16x32_bf16(ld_frag(wfr, F3_BASE + mt * 2 + 0, lane), Bx2[t][0], a3, 0, 0, 0);
            a3 = __builtin_amdgcn_mfma_f32_16x16x32_bf16(ld_frag(wfr, F3_BASE + mt * 2 + 1, lane), Bx2[t][1], a3, 0, 0, 0);
            u32* wp = (u32*)&t3a[rowi * T3AS + mt * 16 + 4 * q];
            wp[0] = pack_trunc(elu_f(a3[0]), elu_f(a3[1]));
            wp[1] = pack_trunc(elu_f(a3[2]), elu_f(a3[3]));
        }
    }
    __syncthreads();

    // conv4 K-step s=0 (k 0..31) from t3a
    for (int t = 0; t < 2; ++t) {
        const int rowi = (wv * 2 + t) * 16 + m;
        bf16x8 Bt = *(const bf16x8*)&t3a[rowi * T3AS + q * 8];
        #pragma unroll
        for (int mt = 0; mt < 3; ++mt)
            acc4[t][mt] = __builtin_amdgcn_mfma_f32_16x16x32_bf16(ld_frag(wfr, F4_BASE + mt * 3 + 0, lane), Bt, acc4[t][mt], 0, 0, 0);
    }
    __syncthreads();   // WAR: conv3B overwrites t3a region

    // conv3 phase B: oc 32..79 -> t3b (cols 0..47)
    for (int t = 0; t < 2; ++t) {
        const int rowi = (wv * 2 + t) * 16 + m;
        #pragma unroll
        for (int mtb = 0; mtb < 3; ++mtb) {
            const int mt = mtb + 2;
            f32x4 a3;
            #pragma unroll
            for (int r = 0; r < 4; ++r) a3[r] = b3[mt * 16 + 4 * q + r];
            a3 = __builtin_amdgcn_mfma_f32_16x16x32_bf16(ld_frag(wfr, F3_BASE + mt * 2 + 0, lane), Bx2[t][0], a3, 0, 0, 0);
            a3 = __builtin_amdgcn_mfma_f32_16x16x32_bf16(ld_frag(wfr, F3_BASE + mt * 2 + 1, lane), Bx2[t][1], a3, 0, 0, 0);
            u32* wp = (u32*)&t3b[rowi * T3BS + mtb * 16 + 4 * q];
            wp[0] = pack_trunc(elu_f(a3[0]), elu_f(a3[1]));
            wp[1] = pack_trunc(elu_f(a3[2]), elu_f(a3[3]));
        }
    }
    __syncthreads();

    // conv4 K-steps s=1 (k 32..63 -> cols 0..31), s=2 (k 64..79 -> cols 32..47) + epilogue
    for (int t = 0; t < 2; ++t) {
        const int rowi = (wv * 2 + t) * 16 + m;
        bf16x8 Bt1 = *(const bf16x8*)&t3b[rowi * T3BS + q * 8];
        bf16x8 Bt2 = *(const bf16x8*)&t3b[rowi * T3BS + ((q < 2) ? (32 + q * 8) : 0)];
        #pragma unroll
        for (int mt = 0; mt < 3; ++mt) {
            acc4[t][mt] = __builtin_amdgcn_mfma_f32_16x16x32_bf16(ld_frag(wfr, F4_BASE + mt * 3 + 1, lane), Bt1, acc4[t][mt], 0, 0, 0);
            acc4[t][mt] = __builtin_amdgcn_mfma_f32_16x16x32_bf16(ld_frag(wfr, F4_BASE + mt * 3 + 2, lane), Bt2, acc4[t][mt], 0, 0, 0);
            int oc0 = mt * 16 + 4 * q;
            if (oc0 < 40) {
                u32* wp = (u32*)&xB[rowi * X2S + oc0];   // x4 overwrites x2 (own rows)
                wp[0] = pack_trunc(elu_f(acc4[t][mt][0]), elu_f(acc4[t][mt][1]));
                wp[1] = pack_trunc(elu_f(acc4[t][mt][2]), elu_f(acc4[t][mt][3]));
            }
        }
    }
    __syncthreads();

    // ---------- conv5: 40->20 k=3 (im2col K=120), f32 bias seed -> x5 ----------
    for (int t = 0; t < 2; ++t) {
        const int rowi = (wv * 2 + t) * 16 + m;
        bf16x8 B5[4];
        #pragma unroll
        for (int s = 0; s < 4; ++s) {
            int k0 = 32 * s + 8 * q;
            int dk, ic0;
            if (k0 < 120) {
                dk = (k0 >= 80) ? 2 : ((k0 >= 40) ? 1 : 0);
                ic0 = k0 - 40 * dk;
            } else { dk = 0; ic0 = 0; }              // valid x4 data x zero-A
            B5[s] = *(const bf16x8*)&xB[(rowi + dk) * X2S + ic0];
        }
        #pragma unroll
        for (int mt = 0; mt < 2; ++mt) {
            f32x4 acc;
            #pragma unroll
            for (int r = 0; r < 4; ++r) {
                int oc = mt * 16 + 4 * q + r;
                acc[r] = (oc < 20) ? b5[oc] : 0.0f;
            }
            #pragma unroll
            for (int s = 0; s < 4; ++s)
                acc = __builtin_amdgcn_mfma_f32_16x16x32_bf16(ld_frag(wfr, F5_BASE + mt * 4 + s, lane), B5[s], acc, 0, 0, 0);
            int oc0 = mt * 16 + 4 * q;
            if (oc0 < 20) {
                u32* wp = (u32*)&x5[rowi * X5S + oc0];
                wp[0] = pack_trunc(elu_f(acc[0]), elu_f(acc[1]));
                wp[1] = pack_trunc(elu_f(acc[2]), elu_f(acc[3]));
            }
        }
    }
    __syncthreads();

    // ---------- conv6: 20->1, sigmoid + 0.1 -> beta (u32-pair reads) ----------
    if (tid < 254) {
        const u32* xp = (const u32*)&x5[tid * X5S];   // 26 even -> 4B aligned
        float a = b6[0];
        #pragma unroll
        for (int p = 0; p < 10; ++p) {
            u32 u = xp[p];
            a += w6[2 * p] * bf_lo(u) + w6[2 * p + 1] * bf_hi(u);
        }
        beta[tid] = 1.0f / (1.0f + __expf(-a)) + 0.1f;
    }
    __syncthreads();

    // ---------- WENO5 ----------
    const float eps = e_ptr[0];
    if (tid < TOUT) {
        int j = J0 + tid;
        if (j < n_out) {
            float a  = s_uu[tid + 5];
            float b  = s_uu[tid + 6];
            float c  = s_uu[tid + 7];
            float d  = s_uu[tid + 8];
            float ee = s_uu[tid + 9];
            float f  = s_uu[tid + 10];
            float m0 = beta[tid];
            float m1 = beta[tid + 1];
            float m2 = beta[tid + 2];

            const float i6 = 1.0f / 6.0f;
            float fp0 = (11.f * d - 7.f * ee + 2.f * f) * i6;
            float fp1 = (2.f * c + 5.f * d - ee) * i6;
            float fp2 = (-b + 5.f * c + 2.f * d) * i6;
            float fn0 = (11.f * c - 7.f * d + 2.f * ee) * i6;
            float fn1 = (2.f * b + 5.f * c - d) * i6;
            float fn2 = (-a + 5.f * b + 2.f * c) * i6;

            const float c1312 = 13.f / 12.f;
            float bp0 = c1312 * sq_f(d - 2.f * ee + f) + 0.25f * sq_f(3.f * d - 4.f * ee + f);
            float bp1 = c1312 * sq_f(c - 2.f * d + ee) + 0.25f * sq_f(c - ee);
            float bp2 = c1312 * sq_f(b - 2.f * c + d) + 0.25f * sq_f(b - 4.f * c + 3.f * d);
            float bn0 = c1312 * sq_f(c - 2.f * d + ee) + 0.25f * sq_f(3.f * c - 4.f * d + ee);
            float bn1 = c1312 * sq_f(b - 2.f * c + d) + 0.25f * sq_f(b - d);
            float bn2 = c1312 * sq_f(a - 2.f * b + c) + 0.25f * sq_f(a - 4.f * b + 3.f * c);

            bp0 *= m0; bp1 *= m1; bp2 *= m2;
            bn0 *= m0; bn1 *= m1; bn2 *= m2;

            float q0 = eps + bp0; q0 *= q0;
            float q1 = eps + bp1; q1 *= q1;
            float q2 = eps + bp2; q2 *= q2;
            float brs = bp2 - bp0; brs *= brs;
            float o0 = 0.1f * (1.f + brs / q0);
            float o1 = 0.6f * (1.f + brs / q1);
            float o2 = 0.3f * (1.f + brs / q2);
            float inv = 1.f / (o0 + o1 + o2);
            float fluxp = (o0 * fp0 + o1 * fp1 + o2 * fp2) * inv;

            q0 = eps + bn0; q0 *= q0;
            q1 = eps + bn1; q1 *= q1;
            q2 = eps + bn2; q2 *= q2;
            brs = bn2 - bn0; brs *= brs;
            o0 = 0.1f * (1.f + brs / q0);
            o1 = 0.6f * (1.f + brs / q1);
            o2 = 0.3f * (1.f + brs / q2);
            inv = 1.f / (o0 + o1 + o2);
            float fluxn = (o0 * fn0 + o1 * fn1 + o2 * fn2) * inv;

            out[j] = fluxp - fluxn;
        }
    }
}

extern "C" void kernel_launch(void* const* d_in, const int* in_sizes, int n_in,
                              void* d_out, int out_size, void* d_ws, size_t ws_size,
                              hipStream_t stream) {
    const float* uu = (const float*)d_in[0];
    const float* e  = (const float*)d_in[1];
    const float* w1 = (const float*)d_in[2];
    const float* b1 = (const float*)d_in[3];
    const float* w2 = (const float*)d_in[4];
    const float* b2 = (const float*)d_in[5];
    const float* w3 = (const float*)d_in[6];
    const float* b3 = (const float*)d_in[7];
    const float* w4 = (const float*)d_in[8];
    const float* b4 = (const float*)d_in[9];
    const float* w5 = (const float*)d_in[10];
    const float* b5 = (const float*)d_in[11];
    const float* w6 = (const float*)d_in[12];
    const float* b6 = (const float*)d_in[13];
    float* out = (float*)d_out;
    u16* wfr = (u16*)d_ws;
    const int N = in_sizes[0];
    const int nblocks = (out_size + TOUT - 1) / TOUT;

    build_frags_kernel<<<NFRAGS, 64, 0, stream>>>(w2, w3, w4, w5, wfr);
    weno_nn_kernel<<<nblocks, NTHREADS, 0, stream>>>(
        uu, e, w1, b1, b2, b3, b4, b5, w6, b6, wfr,
        out, out_size, N);
}

// Round 13
// 310.017 us; speedup vs baseline: 1.0110x; 1.0110x over previous
//
#include <hip/hip_runtime.h>
#include <math.h>

#define NTHREADS 256        // 4 waves; small blocks -> cheap barriers, 7 blocks/CU
#define TOUT 124
#define NP 128              // mid positions, base P0-1
#define X1ROWS 132
#define NDIF 136
#define NUU 138

// element strides (u16)
#define X1S 40              // cols 0..19 data, 20..31 zero (q>=2 frag reads), 32..39 unused
#define X2S 40              // x2 / x4 share xB (rows 0..127 + zero rows 128,129)
#define T3AS 34             // per-wave t3 tile, phase A stride (odd banks)
#define T3BS 50             // phase B stride (odd banks); tile sized 16 x T3BS
#define X5S 26              // odd bank stride for conv6

// smem layout (bytes, 16B aligned)
#define SUU_OFF  0          // float[138] = 552
#define SDIF_OFF 560        // float[136] = 544
#define RA_OFF   1104       // x1(10560) -> t3 tiles(4x1600=6400) -> x5(6656); size 10560
#define RB_OFF   11664      // xB 130x40x2 = 10400 ; beta float[126] overlays
#define SMEM_SIZE 22080     // -> 7 blocks/CU (154.6 KB of 160 KB)

// weight-fragment table in d_ws: 42 frags x 64 lanes x 8 bf16 (16 B) — unchanged
#define F2_BASE 0
#define F3_BASE 15
#define F4_BASE 25
#define F5_BASE 34
#define NFRAGS 42

typedef unsigned short u16;
typedef unsigned int u32;
typedef __attribute__((ext_vector_type(8))) short bf16x8;
typedef __attribute__((ext_vector_type(4))) float f32x4;

// compiler-only fence for same-wave LDS write->read hand-offs (DS is in-order per wave)
#define MEM_FENCE() __asm__ __volatile__("" ::: "memory")

__device__ __forceinline__ float elu_f(float x) {
    return x > 0.0f ? x : (__expf(x) - 1.0f);
}
__device__ __forceinline__ float sq_f(float x) { return x * x; }
__device__ __forceinline__ u16 f2bf(float f) {              // RNE (setup kernel only)
    union { float f; u32 u; } v; v.f = f;
    u32 r = v.u + 0x7FFFu + ((v.u >> 16) & 1u);
    return (u16)(r >> 16);
}
__device__ __forceinline__ float bf_lo(u32 u) {
    union { u32 u; float f; } v; v.u = u << 16; return v.f;
}
__device__ __forceinline__ float bf_hi(u32 u) {
    union { u32 u; float f; } v; v.u = u & 0xFFFF0000u; return v.f;
}
__device__ __forceinline__ u32 pack_trunc(float a, float b) {
    union { float f; u32 u; } va, vb; va.f = a; vb.f = b;
#if __has_builtin(__builtin_amdgcn_perm)
    return __builtin_amdgcn_perm(vb.u, va.u, 0x07060302u);
#else
    return (vb.u & 0xFFFF0000u) | (va.u >> 16);
#endif
}

// ---- setup kernel: build all MFMA A-operand weight frags once per launch ----
__global__ __launch_bounds__(64) void build_frags_kernel(
    const float* __restrict__ w2, const float* __restrict__ w3,
    const float* __restrict__ w4, const float* __restrict__ w5,
    u16* __restrict__ ws)
{
    const int f = blockIdx.x;      // 0..41
    const int lane = threadIdx.x;  // 0..63
    const int m = lane & 15;
    const int q = lane >> 4;
    float wvv[8];
    #pragma unroll
    for (int j = 0; j < 8; ++j) wvv[j] = 0.0f;

    if (f < F3_BASE) {                       // conv2: 20->40 k=5, K = dk*32+ic
        int mt = (f - F2_BASE) / 5, s = (f - F2_BASE) % 5;
        int oc = mt * 16 + m;
        #pragma unroll
        for (int j = 0; j < 8; ++j) {
            int ic = q * 8 + j;
            if (oc < 40 && ic < 20) wvv[j] = w2[oc * 100 + ic * 5 + s];
        }
    } else if (f < F4_BASE) {                // conv3: 40->80 k=1, K=40 pad 64
        int mt = (f - F3_BASE) / 2, s = (f - F3_BASE) % 2;
        int oc = mt * 16 + m;
        #pragma unroll
        for (int j = 0; j < 8; ++j) {
            int k = s * 32 + q * 8 + j;
            if (k < 40) wvv[j] = w3[oc * 40 + k];
        }
    } else if (f < F5_BASE) {                // conv4: 80->40 k=1, K=80 pad 96
        int mt = (f - F4_BASE) / 3, s = (f - F4_BASE) % 3;
        int oc = mt * 16 + m;
        #pragma unroll
        for (int j = 0; j < 8; ++j) {
            int k = s * 32 + q * 8 + j;
            if (oc < 40 && k < 80) wvv[j] = w4[oc * 80 + k];
        }
    } else {                                 // conv5: 40->20 k=3, K=120: k=dk*40+ic
        int mt = (f - F5_BASE) / 4, s = (f - F5_BASE) % 4;
        int oc = mt * 16 + m;
        int k0 = s * 32 + q * 8;
        int dk = k0 / 40, ic0 = k0 - dk * 40;
        #pragma unroll
        for (int j = 0; j < 8; ++j) {
            if (oc < 20 && k0 < 120) wvv[j] = w5[oc * 120 + (ic0 + j) * 3 + dk];
        }
    }
    u32 pk[4];
    #pragma unroll
    for (int p = 0; p < 4; ++p)
        pk[p] = (u32)f2bf(wvv[2 * p]) | ((u32)f2bf(wvv[2 * p + 1]) << 16);
    u32* wp = (u32*)&ws[(f * 64 + lane) * 8];
    wp[0] = pk[0]; wp[1] = pk[1]; wp[2] = pk[2]; wp[3] = pk[3];
}

__device__ __forceinline__ bf16x8 ld_frag(const u16* ws, int f, int lane) {
    return *(const bf16x8*)&ws[(f * 64 + lane) * 8];
}

// plain launch bounds: LDS caps blocks/CU; min-waves bounds caused spills (R5/R10)
__global__ __launch_bounds__(NTHREADS) void weno_nn_kernel(
    const float* __restrict__ uu, const float* __restrict__ e_ptr,
    const float* __restrict__ w1, const float* __restrict__ b1,
    const float* __restrict__ b2, const float* __restrict__ b3,
    const float* __restrict__ b4, const float* __restrict__ b5,
    const float* __restrict__ w6, const float* __restrict__ b6,
    const u16* __restrict__ wfr,
    float* __restrict__ out, int n_out, int N)
{
    __shared__ __align__(16) unsigned char smem[SMEM_SIZE];
    float* s_uu  = (float*)(smem + SUU_OFF);
    float* s_dif = (float*)(smem + SDIF_OFF);
    u16*   x1    = (u16*)(smem + RA_OFF);
    u16*   t3t   = (u16*)(smem + RA_OFF);    // 4 per-wave 16xT3BS tiles, overlays x1
    u16*   x5    = (u16*)(smem + RA_OFF);    // overlays t3 tiles (dead after conv4)
    u16*   xB    = (u16*)(smem + RB_OFF);    // x2 -> x4 (own-row overwrite)
    float* beta  = (float*)(smem + RB_OFF);  // overlays x4 (dead after conv5)

    const int tid  = threadIdx.x;
    const int lane = tid & 63;
    const int wv   = __builtin_amdgcn_readfirstlane(tid >> 6);   // 0..3
    const int m    = lane & 15;
    const int q    = lane >> 4;
    const int J0   = blockIdx.x * TOUT;
    const int P0   = J0 + 2;
    const int U0   = J0 - 4;

    // ---------- stage 0: uu tile ----------
    for (int i = tid; i < NUU; i += NTHREADS) {
        int g = U0 + i;
        s_uu[i] = (g >= 0 && g < N) ? uu[g] : 0.0f;
    }
    __syncthreads();

    // ---------- avg-diff ----------
    for (int d = tid; d < NDIF; d += NTHREADS) {
        int g = P0 - 5 + d;
        float v = 0.0f;
        if (g >= 0 && g < N) {
            int j1 = g < N - 2 ? g : N - 2;
            int j0 = g - 1 > 0 ? g - 1 : 0;
            float dl = s_uu[j1 + 1 - U0] - s_uu[j1 - U0];
            float dr = s_uu[j0 + 1 - U0] - s_uu[j0 - U0];
            v = 0.5f * (dl + dr);
        }
        s_dif[d] = v;
    }
    __syncthreads();

    // ---------- conv1 (VALU): 1->20, k=5, elu -> x1[row][ic] ----------
    // also zero x4 rows 128,129 (conv5 right-edge reads)
    if (tid >= 128 && tid < 168) ((u32*)&xB[128 * X2S])[tid - 128] = 0;
    if (tid < X1ROWS) {
        const int s = tid;
        int g = P0 - 3 + s;
        bool valid = (g >= 0 && g < N);
        float dv[5];
        #pragma unroll
        for (int k = 0; k < 5; ++k) dv[k] = s_dif[s + k];
        float v[20];
        #pragma unroll
        for (int oc = 0; oc < 20; ++oc) {
            float a = b1[oc];
            #pragma unroll
            for (int k = 0; k < 5; ++k) a += w1[oc * 5 + k] * dv[k];
            v[oc] = valid ? elu_f(a) : 0.0f;
        }
        u32* rp = (u32*)&x1[s * X1S];
        #pragma unroll
        for (int p = 0; p < 10; ++p)
            rp[p] = pack_trunc(v[2 * p], v[2 * p + 1]);
        #pragma unroll
        for (int p = 10; p < 16; ++p) rp[p] = 0;     // zero-pad ic 20..31
    }
    __syncthreads();

    // ---------- conv2: 20->40, k=5 (im2col K=160) -> xB(x2) ----------
    {
        f32x4 bias2[3];
        #pragma unroll
        for (int mt = 0; mt < 3; ++mt) {
            #pragma unroll
            for (int r = 0; r < 4; ++r) {
                int oc = mt * 16 + 4 * q + r;
                bias2[mt][r] = (oc < 40) ? b2[oc] : 0.0f;
            }
        }
        for (int t = 0; t < 2; ++t) {
            const int rowi = (wv * 2 + t) * 16 + m;
            f32x4 acc[3];
            #pragma unroll
            for (int mt = 0; mt < 3; ++mt) acc[mt] = bias2[mt];
            #pragma unroll
            for (int s = 0; s < 5; ++s) {
                bf16x8 bfrag = *(const bf16x8*)&x1[(rowi + s) * X1S + q * 8];
                #pragma unroll
                for (int mt = 0; mt < 3; ++mt)
                    acc[mt] = __builtin_amdgcn_mfma_f32_16x16x32_bf16(
                        ld_frag(wfr, F2_BASE + mt * 5 + s, lane), bfrag, acc[mt], 0, 0, 0);
            }
            #pragma unroll
            for (int mt = 0; mt < 3; ++mt) {
                int oc0 = mt * 16 + 4 * q;
                if (oc0 < 40) {
                    u32* wp = (u32*)&xB[rowi * X2S + oc0];
                    wp[0] = pack_trunc(elu_f(acc[mt][0]), elu_f(acc[mt][1]));
                    wp[1] = pack_trunc(elu_f(acc[mt][2]), elu_f(acc[mt][3]));
                }
            }
        }
    }
    __syncthreads();   // x1 -> t3 WAR (t3 tiles overlay x1)

    // ---------- fused conv3/conv4 split-K through per-wave t3 tile (no barriers) ----------
    {
        u16* t3w = t3t + wv * (16 * T3BS);           // this wave's private 1.6 KB tile
        for (int t = 0; t < 2; ++t) {
            const int rowi = (wv * 2 + t) * 16 + m;
            bf16x8 Bx2_0 = *(const bf16x8*)&xB[rowi * X2S + q * 8];                 // k 0..31
            bf16x8 Bx2_1 = *(const bf16x8*)&xB[rowi * X2S + ((q == 0) ? 32 : 0)];   // k 32..39

            // conv3 phase A: oc 0..31 -> tile stride T3AS
            #pragma unroll
            for (int mt = 0; mt < 2; ++mt) {
                f32x4 a3;
                #pragma unroll
                for (int r = 0; r < 4; ++r) a3[r] = b3[mt * 16 + 4 * q + r];
                a3 = __builtin_amdgcn_mfma_f32_16x16x32_bf16(ld_frag(wfr, F3_BASE + mt * 2 + 0, lane), Bx2_0, a3, 0, 0, 0);
                a3 = __builtin_amdgcn_mfma_f32_16x16x32_bf16(ld_frag(wfr, F3_BASE + mt * 2 + 1, lane), Bx2_1, a3, 0, 0, 0);
                u32* wp = (u32*)&t3w[m * T3AS + mt * 16 + 4 * q];
                wp[0] = pack_trunc(elu_f(a3[0]), elu_f(a3[1]));
                wp[1] = pack_trunc(elu_f(a3[2]), elu_f(a3[3]));
            }
            MEM_FENCE();
            // conv4 K-step s=0 (k 0..31)
            f32x4 acc4[3];
            #pragma unroll
            for (int mt = 0; mt < 3; ++mt) {
                #pragma unroll
                for (int r = 0; r < 4; ++r) {
                    int oc = mt * 16 + 4 * q + r;
                    acc4[mt][r] = (oc < 40) ? b4[oc] : 0.0f;
                }
            }
            {
                bf16x8 Bt = *(const bf16x8*)&t3w[m * T3AS + q * 8];
                #pragma unroll
                for (int mt = 0; mt < 3; ++mt)
                    acc4[mt] = __builtin_amdgcn_mfma_f32_16x16x32_bf16(ld_frag(wfr, F4_BASE + mt * 3 + 0, lane), Bt, acc4[mt], 0, 0, 0);
            }
            MEM_FENCE();   // tile read done before phase-B overwrite (same-wave order)
            // conv3 phase B: oc 32..79 -> tile stride T3BS (cols 0..47)
            #pragma unroll
            for (int mtb = 0; mtb < 3; ++mtb) {
                const int mt = mtb + 2;
                f32x4 a3;
                #pragma unroll
                for (int r = 0; r < 4; ++r) a3[r] = b3[mt * 16 + 4 * q + r];
                a3 = __builtin_amdgcn_mfma_f32_16x16x32_bf16(ld_frag(wfr, F3_BASE + mt * 2 + 0, lane), Bx2_0, a3, 0, 0, 0);
                a3 = __builtin_amdgcn_mfma_f32_16x16x32_bf16(ld_frag(wfr, F3_BASE + mt * 2 + 1, lane), Bx2_1, a3, 0, 0, 0);
                u32* wp = (u32*)&t3w[m * T3BS + mtb * 16 + 4 * q];
                wp[0] = pack_trunc(elu_f(a3[0]), elu_f(a3[1]));
                wp[1] = pack_trunc(elu_f(a3[2]), elu_f(a3[3]));
            }
            MEM_FENCE();
            // conv4 K-steps s=1 (k 32..63), s=2 (k 64..79) + epilogue -> x4
            {
                bf16x8 Bt1 = *(const bf16x8*)&t3w[m * T3BS + q * 8];
                bf16x8 Bt2 = *(const bf16x8*)&t3w[m * T3BS + ((q < 2) ? (32 + q * 8) : 0)];
                #pragma unroll
                for (int mt = 0; mt < 3; ++mt) {
                    acc4[mt] = __builtin_amdgcn_mfma_f32_16x16x32_bf16(ld_frag(wfr, F4_BASE + mt * 3 + 1, lane), Bt1, acc4[mt], 0, 0, 0);
                    acc4[mt] = __builtin_amdgcn_mfma_f32_16x16x32_bf16(ld_frag(wfr, F4_BASE + mt * 3 + 2, lane), Bt2, acc4[mt], 0, 0, 0);
                    int oc0 = mt * 16 + 4 * q;
                    if (oc0 < 40) {
                        u32* wp = (u32*)&xB[rowi * X2S + oc0];   // x4 overwrites x2 (own rows)
                        wp[0] = pack_trunc(elu_f(acc4[mt][0]), elu_f(acc4[mt][1]));
                        wp[1] = pack_trunc(elu_f(acc4[mt][2]), elu_f(acc4[mt][3]));
                    }
                }
            }
            MEM_FENCE();   // tile reads done before next t overwrites
        }
    }
    __syncthreads();   // x4 cross-wave reads (conv5) + t3 -> x5 WAR

    // ---------- conv5: 40->20 k=3 (im2col K=120) -> x5 ----------
    for (int t = 0; t < 2; ++t) {
        const int rowi = (wv * 2 + t) * 16 + m;
        bf16x8 B5[4];
        #pragma unroll
        for (int s = 0; s < 4; ++s) {
            int k0 = 32 * s + 8 * q;
            int dk, ic0;
            if (k0 < 120) {
                dk = (k0 >= 80) ? 2 : ((k0 >= 40) ? 1 : 0);
                ic0 = k0 - 40 * dk;
            } else { dk = 0; ic0 = 0; }              // valid x4 data x zero-A
            B5[s] = *(const bf16x8*)&xB[(rowi + dk) * X2S + ic0];
        }
        #pragma unroll
        for (int mt = 0; mt < 2; ++mt) {
            f32x4 acc;
            #pragma unroll
            for (int r = 0; r < 4; ++r) {
                int oc = mt * 16 + 4 * q + r;
                acc[r] = (oc < 20) ? b5[oc] : 0.0f;
            }
            #pragma unroll
            for (int s = 0; s < 4; ++s)
                acc = __builtin_amdgcn_mfma_f32_16x16x32_bf16(ld_frag(wfr, F5_BASE + mt * 4 + s, lane), B5[s], acc, 0, 0, 0);
            int oc0 = mt * 16 + 4 * q;
            if (oc0 < 20) {
                u32* wp = (u32*)&x5[rowi * X5S + oc0];
                wp[0] = pack_trunc(elu_f(acc[0]), elu_f(acc[1]));
                wp[1] = pack_trunc(elu_f(acc[2]), elu_f(acc[3]));
            }
        }
    }
    __syncthreads();

    // ---------- conv6: 20->1, sigmoid + 0.1 -> beta ----------
    if (tid < TOUT + 2) {
        const u32* xp = (const u32*)&x5[tid * X5S];   // stride 52 B, 4-aligned
        float a = b6[0];
        #pragma unroll
        for (int p = 0; p < 10; ++p) {
            u32 u = xp[p];
            a += w6[2 * p] * bf_lo(u) + w6[2 * p + 1] * bf_hi(u);
        }
        beta[tid] = 1.0f / (1.0f + __expf(-a)) + 0.1f;
    }
    __syncthreads();

    // ---------- WENO5 ----------
    const float eps = e_ptr[0];
    if (tid < TOUT) {
        int j = J0 + tid;
        if (j < n_out) {
            float a  = s_uu[tid + 5];
            float b  = s_uu[tid + 6];
            float c  = s_uu[tid + 7];
            float d  = s_uu[tid + 8];
            float ee = s_uu[tid + 9];
            float f  = s_uu[tid + 10];
            float m0 = beta[tid];
            float m1 = beta[tid + 1];
            float m2 = beta[tid + 2];

            const float i6 = 1.0f / 6.0f;
            float fp0 = (11.f * d - 7.f * ee + 2.f * f) * i6;
            float fp1 = (2.f * c + 5.f * d - ee) * i6;
            float fp2 = (-b + 5.f * c + 2.f * d) * i6;
            float fn0 = (11.f * c - 7.f * d + 2.f * ee) * i6;
            float fn1 = (2.f * b + 5.f * c - d) * i6;
            float fn2 = (-a + 5.f * b + 2.f * c) * i6;

            const float c1312 = 13.f / 12.f;
            float bp0 = c1312 * sq_f(d - 2.f * ee + f) + 0.25f * sq_f(3.f * d - 4.f * ee + f);
            float bp1 = c1312 * sq_f(c - 2.f * d + ee) + 0.25f * sq_f(c - ee);
            float bp2 = c1312 * sq_f(b - 2.f * c + d) + 0.25f * sq_f(b - 4.f * c + 3.f * d);
            float bn0 = c1312 * sq_f(c - 2.f * d + ee) + 0.25f * sq_f(3.f * c - 4.f * d + ee);
            float bn1 = c1312 * sq_f(b - 2.f * c + d) + 0.25f * sq_f(b - d);
            float bn2 = c1312 * sq_f(a - 2.f * b + c) + 0.25f * sq_f(a - 4.f * b + 3.f * c);

            bp0 *= m0; bp1 *= m1; bp2 *= m2;
            bn0 *= m0; bn1 *= m1; bn2 *= m2;

            float q0 = eps + bp0; q0 *= q0;
            float q1 = eps + bp1; q1 *= q1;
            float q2 = eps + bp2; q2 *= q2;
            float brs = bp2 - bp0; brs *= brs;
            float o0 = 0.1f * (1.f + brs / q0);
            float o1 = 0.6f * (1.f + brs / q1);
            float o2 = 0.3f * (1.f + brs / q2);
            float inv = 1.f / (o0 + o1 + o2);
            float fluxp = (o0 * fp0 + o1 * fp1 + o2 * fp2) * inv;

            q0 = eps + bn0; q0 *= q0;
            q1 = eps + bn1; q1 *= q1;
            q2 = eps + bn2; q2 *= q2;
            brs = bn2 - bn0; brs *= brs;
            o0 = 0.1f * (1.f + brs / q0);
            o1 = 0.6f * (1.f + brs / q1);
            o2 = 0.3f * (1.f + brs / q2);
            inv = 1.f / (o0 + o1 + o2);
            float fluxn = (o0 * fn0 + o1 * fn1 + o2 * fn2) * inv;

            out[j] = fluxp - fluxn;
        }
    }
}

extern "C" void kernel_launch(void* const* d_in, const int* in_sizes, int n_in,
                              void* d_out, int out_size, void* d_ws, size_t ws_size,
                              hipStream_t stream) {
    const float* uu = (const float*)d_in[0];
    const float* e  = (const float*)d_in[1];
    const float* w1 = (const float*)d_in[2];
    const float* b1 = (const float*)d_in[3];
    const float* w2 = (const float*)d_in[4];
    const float* b2 = (const float*)d_in[5];
    const float* w3 = (const float*)d_in[6];
    const float* b3 = (const float*)d_in[7];
    const float* w4 = (const float*)d_in[8];
    const float* b4 = (const float*)d_in[9];
    const float* w5 = (const float*)d_in[10];
    const float* b5 = (const float*)d_in[11];
    const float* w6 = (const float*)d_in[12];
    const float* b6 = (const float*)d_in[13];
    float* out = (float*)d_out;
    u16* wfr = (u16*)d_ws;
    const int N = in_sizes[0];
    const int nblocks = (out_size + TOUT - 1) / TOUT;

    build_frags_kernel<<<NFRAGS, 64, 0, stream>>>(w2, w3, w4, w5, wfr);
    weno_nn_kernel<<<nblocks, NTHREADS, 0, stream>>>(
        uu, e, w1, b1, b2, b3, b4, b5, w6, b6, wfr,
        out, out_size, N);
}